// Round 7
// baseline (216.734 us; speedup 1.0000x reference)
//
#include <hip/hip_runtime.h>
#include <hip/hip_bf16.h>

#define BATCH 16
#define NH    8
#define CH    8
#define HH    56
#define WW    56
#define POS   3136          // 56*56 = 49*64
#define QKVC  192
#define OC    64
#define SCALE 0.17677669529663687f   // 32^-0.5

typedef unsigned short ushort_t;
typedef __attribute__((ext_vector_type(8))) short bf16x8;   // 8 bf16 = 4 VGPRs
typedef __attribute__((ext_vector_type(4))) float f32x4;

__device__ __forceinline__ unsigned short f2b(float f) {
    __hip_bfloat16 h = __float2bfloat16(f);
    union { __hip_bfloat16 h; unsigned short u; } c; c.h = h; return c.u;
}
__device__ __forceinline__ unsigned int pk(float lo, float hi) {
    return (unsigned int)f2b(lo) | ((unsigned int)f2b(hi) << 16);
}
__device__ __forceinline__ float bu2f(ushort_t u) {
    union { unsigned int v; float f; } c; c.v = ((unsigned int)u) << 16; return c.f;
}
__device__ __forceinline__ float lo2f(unsigned int w) {       // low bf16 -> f32
    union { unsigned int v; float f; } c; c.v = w << 16; return c.f;
}
__device__ __forceinline__ float hi2f(unsigned int w) {       // high bf16 -> f32
    union { unsigned int v; float f; } c; c.v = w & 0xffff0000u; return c.f;
}
// async 16B global->LDS (lane-linear dest within wave)
__device__ __forceinline__ void gll16(const ushort_t* g, ushort_t* l) {
    __builtin_amdgcn_global_load_lds((const __attribute__((address_space(1))) void*)g,
                                     (__attribute__((address_space(3))) void*)l, 16, 0, 0);
}

// ---------------------------------------------------------------------------
// prep_w: qkv_w (192x256) + proj_w (256x64) fp32 -> bf16, PLUS fused attn
// weight tensor wattn[h][ch][ka][12] = {w0..w8, db+rpb, db, 0}.
// grid(67), 256 thr.
// ---------------------------------------------------------------------------
__global__ __launch_bounds__(256) void prep_w(const float* __restrict__ wq,
                                              const float* __restrict__ wp,
                                              const float* __restrict__ dc_b,
                                              const float* __restrict__ dc1_w,
                                              const float* __restrict__ dc1_b,
                                              const float* __restrict__ rpb,
                                              ushort_t* __restrict__ wq16,
                                              ushort_t* __restrict__ wp16,
                                              float* __restrict__ wattn) {
    int idx = blockIdx.x * 256 + threadIdx.x;   // 16384 float4 units + wattn slots
    if (idx >= 16384) {
        int t = idx - 16384;                    // need 576 = 8h * 72(ch*9+ka)
        if (t < 576) {
            int h = t / 72, r = t - h * 72;     // r = ch*9 + ka
            int ka = r % 9;
            float db = dc_b[r] + dc1_b[r];
            float* w = wattn + t * 12;          // t == (h*8+ch)*9 + ka
            #pragma unroll
            for (int j = 0; j < 9; ++j) w[j] = dc1_w[r * 9 + j];
            w[9]  = db + rpb[h * 9 + ka];       // K-branch bias (incl. rpb)
            w[10] = db;                         // V-branch bias
            w[11] = 0.f;
        }
        return;
    }
    const float* src; ushort_t* dst; int off;
    if (idx < 12288) { src = wq; dst = wq16; off = idx * 4; }
    else             { src = wp; dst = wp16; off = (idx - 12288) * 4; }
    float4 v = *(const float4*)(src + off);
    uint2 st = { pk(v.x, v.y), pk(v.z, v.w) };
    *(uint2*)(dst + off) = st;
}

// ---------------------------------------------------------------------------
// qkv v3: fused A-transpose, ONE N-half per block (back to grid (49,2,16)).
// Removes R6's in-block restage + 2 barriers; doubles block parallelism.
// x's second read (other half-block) is L3-resident. Mtile=64, Ntile=96,
// K=256. LDS 80KB = 2 blk/CU. grid (49, 2, 16), 256 thr.
// ---------------------------------------------------------------------------
__global__ __launch_bounds__(256) void qkv_mfma(const float* __restrict__ x,
                                                const ushort_t* __restrict__ wq16,
                                                const float* __restrict__ bias,
                                                ushort_t* __restrict__ f16) {
    __shared__ __align__(16) ushort_t wa[64 * 256];
    __shared__ __align__(16) ushort_t wb[96 * 256];
    const int tid = threadIdx.x;
    const int p0 = blockIdx.x * 64, o0 = blockIdx.y * 96, b = blockIdx.z;

    // B: async GLL (rows 512B, chunk q stored at q^(n&7))
    #pragma unroll
    for (int it = 0; it < 12; ++it) {
        int idx = it * 256 + tid;
        int n = idx >> 5, q = idx & 31, qs = q ^ (n & 7);
        gll16(wq16 + (size_t)(o0 + n) * 256 + qs * 8, &wb[idx * 8]);
    }

    // A: fused transpose from x fp32 (overlaps the async B loads).
    // Lane p, octet q: 8 ch-strided scalar loads (each instr 256B coalesced),
    // pack to bf16, ds_write_b128 at XOR-swizzled chunk (same layout the
    // old gll16 path produced; XOR is an involution).
    const int p = tid & 63;             // pos within tile
    const int w = tid >> 6;             // wave id 0..3
    {
        const float* xp = x + (size_t)b * 256 * POS + p0 + p;
        #pragma unroll
        for (int it = 0; it < 8; ++it) {
            int q = it * 4 + w;         // ch-octet 0..31
            const float* xc = xp + (size_t)q * 8 * POS;
            uint4 st = { pk(xc[0],       xc[POS]),
                         pk(xc[2 * POS], xc[3 * POS]),
                         pk(xc[4 * POS], xc[5 * POS]),
                         pk(xc[6 * POS], xc[7 * POS]) };
            *(uint4*)&wa[p * 256 + ((q ^ (p & 7)) * 8)] = st;
        }
    }
    __syncthreads();

    const int lane = tid & 63;
    const int wid  = tid >> 6;
    const int m0   = wid * 16;
    const int ml   = lane & 15;
    const int kg   = lane >> 4;

    f32x4 acc[6];
    #pragma unroll
    for (int u = 0; u < 6; ++u) acc[u] = (f32x4){0.f, 0.f, 0.f, 0.f};

    #pragma unroll
    for (int ks = 0; ks < 8; ++ks) {
        const int pj = ((ks * 4 + kg) ^ (ml & 7)) * 8;   // swizzled chunk
        bf16x8 af = *(const bf16x8*)&wa[(m0 + ml) * 256 + pj];
        #pragma unroll
        for (int u = 0; u < 6; ++u) {
            bf16x8 bf = *(const bf16x8*)&wb[(u * 16 + ml) * 256 + pj];
            acc[u] = __builtin_amdgcn_mfma_f32_16x16x32_bf16(af, bf, acc[u], 0, 0, 0);
        }
    }

    #pragma unroll
    for (int u = 0; u < 6; ++u) {
        int o = o0 + u * 16 + ml;
        float bj = bias[o];
        uint2 st = { pk(acc[u][0] + bj, acc[u][1] + bj),
                     pk(acc[u][2] + bj, acc[u][3] + bj) };
        *(uint2*)(f16 + ((size_t)b * QKVC + o) * POS + p0 + m0 + kg * 4) = st;
    }
}

// ---------------------------------------------------------------------------
// attn v7: R5/R6 proven body; OUTPUT now bf16 in [b][pos][64] layout --
// one uint4 store per thread (vs 8 scalar fp32 stores), halves a-traffic,
// numerically free (proj converted to bf16 for MFMA anyway). Slot for head
// h = columns h*8..h*8+7 of the 64-wide row.
// TBH=8, grid (7, 8, 16), 448 thr, LDS 19.2 KB.
// ---------------------------------------------------------------------------
#define TBH 8
#define HROW (TBH + 2)              // 10
#define HCOL 60                     // padded: [0]unused [1]L [2..57]int [58]R [59]unused
__global__ __launch_bounds__(448) void attn_kernel(const ushort_t* __restrict__ f16,
                                                   const float* __restrict__ wattn,
                                                   ushort_t* __restrict__ a16) {
    __shared__ __align__(16) unsigned int kvbuf[CH][HROW][HCOL];  // k | (v<<16)

    const int tid = threadIdx.x;
    const int ty0 = blockIdx.x * TBH;
    const int h   = blockIdx.y;
    const int b   = blockIdx.z;
    const ushort_t* fb = f16 + ((size_t)b * QKVC + h * 24) * POS;

    const int ly  = tid / WW;           // 0..7
    const int lx  = tid - ly * WW;
    const int pos = (ty0 + ly) * WW + lx;

    // q loads issued BEFORE staging: latency overlaps the stage loop
    float q[CH];
    #pragma unroll
    for (int ch = 0; ch < CH; ++ch) q[ch] = bu2f(fb[ch * POS + pos]) * SCALE;

    // zero L/R border columns (incl. corner rows)
    if (tid < 80) {
        int ch = tid / 10, row = tid - ch * 10;
        kvbuf[ch][row][1]  = 0;
        kvbuf[ch][row][58] = 0;
    }
    // interior: 8ch x 10row x 28 dword-pairs = 2240 tasks, 5 per thread
    #pragma unroll
    for (int it = 0; it < 5; ++it) {
        int idx  = it * 448 + tid;
        int ch   = idx / 280;
        int rem  = idx - ch * 280;
        int row  = rem / 28;
        int dcol = rem - row * 28;
        int gy   = ty0 + row - 1;
        unsigned int kk = 0, vv = 0;
        if (gy >= 0 && gy < HH) {           // wave-mostly-uniform row check
            int o = gy * WW + dcol * 2;
            kk = *(const unsigned int*)(fb + (8  + ch) * POS + o);
            vv = *(const unsigned int*)(fb + (16 + ch) * POS + o);
        }
        uint2 w;
        w.x = (kk & 0xffffu) | (vv << 16);
        w.y = (kk >> 16)     | (vv & 0xffff0000u);
        *(uint2*)&kvbuf[ch][row][2 + dcol * 2] = w;
    }
    __syncthreads();

    // per-(h,ch) fused weights: uniform -> s_load quads
    const float4* wh = (const float4*)wattn + (size_t)h * 8 * 27;

    // ---- pass 1: K-conv -> logits ----
    float logits[9];
    #pragma unroll
    for (int ka = 0; ka < 9; ++ka) logits[ka] = 0.f;
    #pragma unroll
    for (int ch = 0; ch < CH; ++ch) {
        float nk[9];
        #pragma unroll
        for (int dy = 0; dy < 3; ++dy)
            #pragma unroll
            for (int dx = 0; dx < 3; ++dx)
                nk[dy * 3 + dx] = lo2f(kvbuf[ch][ly + dy][lx + 1 + dx]);
        const float qc = q[ch];
        const float4* wp = wh + ch * 27;
        #pragma unroll
        for (int ka = 0; ka < 9; ++ka) {
            float4 a4 = wp[ka * 3 + 0];
            float4 b4 = wp[ka * 3 + 1];
            float4 c4 = wp[ka * 3 + 2];
            float kv = nk[ka] + c4.y;
            kv += nk[0]*a4.x + nk[1]*a4.y + nk[2]*a4.z + nk[3]*a4.w;
            kv += nk[4]*b4.x + nk[5]*b4.y + nk[6]*b4.z + nk[7]*b4.w;
            kv += nk[8]*c4.x;
            logits[ka] += qc * kv;
        }
    }

    // ---- softmax ----
    float m = logits[0];
    #pragma unroll
    for (int ka = 1; ka < 9; ++ka) m = fmaxf(m, logits[ka]);
    float att[9];
    float s = 0.f;
    #pragma unroll
    for (int ka = 0; ka < 9; ++ka) { att[ka] = __expf(logits[ka] - m); s += att[ka]; }
    float inv = 1.f / s;
    #pragma unroll
    for (int ka = 0; ka < 9; ++ka) att[ka] *= inv;

    // ---- pass 2: V-conv -> weighted sum ----
    float outv[CH];
    #pragma unroll
    for (int ch = 0; ch < CH; ++ch) {
        float nv[9];
        #pragma unroll
        for (int dy = 0; dy < 3; ++dy)
            #pragma unroll
            for (int dx = 0; dx < 3; ++dx)
                nv[dy * 3 + dx] = hi2f(kvbuf[ch][ly + dy][lx + 1 + dx]);
        const float4* wp = wh + ch * 27;
        float o = 0.f;
        #pragma unroll
        for (int ka = 0; ka < 9; ++ka) {
            float4 a4 = wp[ka * 3 + 0];
            float4 b4 = wp[ka * 3 + 1];
            float4 c4 = wp[ka * 3 + 2];
            float vv = nv[ka] + c4.z;
            vv += nv[0]*a4.x + nv[1]*a4.y + nv[2]*a4.z + nv[3]*a4.w;
            vv += nv[4]*b4.x + nv[5]*b4.y + nv[6]*b4.z + nv[7]*b4.w;
            vv += nv[8]*c4.x;
            o += att[ka] * vv;
        }
        outv[ch] = o;
    }
    // single 16B store: a16[b][pos][h*8 .. h*8+7] bf16
    uint4 st = { pk(outv[0], outv[1]), pk(outv[2], outv[3]),
                 pk(outv[4], outv[5]), pk(outv[6], outv[7]) };
    *(uint4*)(a16 + ((size_t)b * POS + pos) * 64 + h * 8) = st;
}
#undef TBH

// ---------------------------------------------------------------------------
// proj v2: A is now bf16 [b][pos][64] (K-contiguous 128B rows) -> staged
// directly with global_load_lds (2 iters), XOR-swizzled like wb. Whole fp32
// front-end (16KB ld buffer + pack pass + 2 barriers) eliminated.
// LDS 24KB -> 6 blk/CU. Mtile=64, Ntile=128. grid (49, 2, 16), 256 thr.
// ---------------------------------------------------------------------------
__global__ __launch_bounds__(256) void proj_mfma(const ushort_t* __restrict__ a16,
                                                 const ushort_t* __restrict__ wp16,
                                                 const float* __restrict__ bias,
                                                 float* __restrict__ out) {
    __shared__ __align__(16) ushort_t wa[64 * 64];
    __shared__ __align__(16) ushort_t wb[128 * 64];
    const int tid = threadIdx.x;
    const int p0 = blockIdx.x * 64, o0 = blockIdx.y * 128, b = blockIdx.z;

    // A: 64 rows x 8 chunks = 512 tasks (rows 128B, chunk q at q^(p&7))
    const ushort_t* ab = a16 + ((size_t)b * POS + p0) * 64;
    #pragma unroll
    for (int it = 0; it < 2; ++it) {
        int idx = it * 256 + tid;
        int p = idx >> 3, q = idx & 7, qs = q ^ (p & 7);
        gll16(ab + (size_t)p * 64 + qs * 8, &wa[idx * 8]);
    }
    // B: 128 rows x 8 chunks = 1024 tasks (pre-swizzled wp16)
    #pragma unroll
    for (int it = 0; it < 4; ++it) {
        int idx = it * 256 + tid;
        int n = idx >> 3, q = idx & 7, qs = q ^ (n & 7);
        gll16(wp16 + (size_t)(o0 + n) * 64 + qs * 8, &wb[idx * 8]);
    }
    __syncthreads();

    const int lane = tid & 63;
    const int wid  = tid >> 6;
    const int m0   = wid * 16;
    const int ml   = lane & 15;
    const int kg   = lane >> 4;

    f32x4 acc[8];
    #pragma unroll
    for (int u = 0; u < 8; ++u) acc[u] = (f32x4){0.f, 0.f, 0.f, 0.f};

    #pragma unroll
    for (int s = 0; s < 2; ++s) {
        const int pj = ((s * 4 + kg) ^ (ml & 7)) * 8;    // swizzled chunk
        bf16x8 af = *(const bf16x8*)&wa[(m0 + ml) * 64 + pj];
        #pragma unroll
        for (int u = 0; u < 8; ++u) {
            bf16x8 bf = *(const bf16x8*)&wb[(u * 16 + ml) * 64 + pj];
            acc[u] = __builtin_amdgcn_mfma_f32_16x16x32_bf16(af, bf, acc[u], 0, 0, 0);
        }
    }

    #pragma unroll
    for (int u = 0; u < 8; ++u) {
        int o = o0 + u * 16 + ml;
        float bj = bias[o];
        float4 st = { acc[u][0] + bj, acc[u][1] + bj, acc[u][2] + bj, acc[u][3] + bj };
        *(float4*)(out + ((size_t)b * 256 + o) * POS + p0 + m0 + kg * 4) = st;
    }
}

// ---------------------------------------------------------------------------
extern "C" void kernel_launch(void* const* d_in, const int* in_sizes, int n_in,
                              void* d_out, int out_size, void* d_ws, size_t ws_size,
                              hipStream_t stream) {
    const float* x      = (const float*)d_in[0];
    const float* qkv_w  = (const float*)d_in[1];
    const float* qkv_b  = (const float*)d_in[2];
    const float* dc_b   = (const float*)d_in[3];
    const float* dc1_w  = (const float*)d_in[4];
    const float* dc1_b  = (const float*)d_in[5];
    const float* rpb    = (const float*)d_in[6];
    const float* proj_w = (const float*)d_in[7];
    const float* proj_b = (const float*)d_in[8];
    float* out = (float*)d_out;

    // ws layout (25.8 MB base):
    //   f16   bf16 16*192*3136     = 19.27 MB
    //   a16   bf16 16*3136*64      =  6.42 MB   ([b][pos][64], attn -> proj)
    //   wq16  96 KB, wp16 32 KB
    //   wattn 27 KB -- d_out fallback if ws exact (proj rewrites all of out).
    ushort_t* f16  = (ushort_t*)d_ws;
    ushort_t* a16  = f16 + (size_t)BATCH * QKVC * POS;
    ushort_t* wq16 = a16 + (size_t)BATCH * POS * 64;
    ushort_t* wp16 = wq16 + 192 * 256;

    const size_t WS_BASE = 25821184;        // bytes used by the four bufs above
    float* wattn = (ws_size >= WS_BASE + 6912 * sizeof(float))
                 ? (float*)((char*)d_ws + WS_BASE)
                 : (float*)d_out;           // scratch; proj rewrites all of out

    prep_w   <<<dim3(67),           256, 0, stream>>>(qkv_w, proj_w, dc_b, dc1_w,
                                                      dc1_b, rpb, wq16, wp16, wattn);
    qkv_mfma <<<dim3(49, 2, BATCH), 256, 0, stream>>>(x, wq16, qkv_b, f16);
    attn_kernel<<<dim3(7, NH, BATCH), 448, 0, stream>>>(f16, wattn, a16);
    proj_mfma<<<dim3(49, 2, BATCH), 256, 0, stream>>>(a16, wp16, proj_b, out);
}

// Round 8
// 180.366 us; speedup vs baseline: 1.2016x; 1.2016x over previous
//
#include <hip/hip_runtime.h>
#include <hip/hip_bf16.h>

#define BATCH 16
#define NH    8
#define CH    8
#define HH    56
#define WW    56
#define POS   3136          // 56*56 = 49*64
#define QKVC  192
#define OC    64
#define SCALE 0.17677669529663687f   // 32^-0.5

typedef unsigned short ushort_t;
typedef __attribute__((ext_vector_type(8))) short bf16x8;   // 8 bf16 = 4 VGPRs
typedef __attribute__((ext_vector_type(4))) float f32x4;

__device__ __forceinline__ unsigned short f2b(float f) {
    __hip_bfloat16 h = __float2bfloat16(f);
    union { __hip_bfloat16 h; unsigned short u; } c; c.h = h; return c.u;
}
__device__ __forceinline__ unsigned int pk(float lo, float hi) {
    return (unsigned int)f2b(lo) | ((unsigned int)f2b(hi) << 16);
}
__device__ __forceinline__ float bu2f(ushort_t u) {
    union { unsigned int v; float f; } c; c.v = ((unsigned int)u) << 16; return c.f;
}
__device__ __forceinline__ float lo2f(unsigned int w) {       // low bf16 -> f32
    union { unsigned int v; float f; } c; c.v = w << 16; return c.f;
}
__device__ __forceinline__ float hi2f(unsigned int w) {       // high bf16 -> f32
    union { unsigned int v; float f; } c; c.v = w & 0xffff0000u; return c.f;
}
// async 16B global->LDS (lane-linear dest within wave)
__device__ __forceinline__ void gll16(const ushort_t* g, ushort_t* l) {
    __builtin_amdgcn_global_load_lds((const __attribute__((address_space(1))) void*)g,
                                     (__attribute__((address_space(3))) void*)l, 16, 0, 0);
}

// ---------------------------------------------------------------------------
// prep_w: qkv_w (192x256) + proj_w (256x64) fp32 -> bf16, PLUS fused attn
// weight tensor wattn[h][ch][ka][12] = {w0..w8, db+rpb, db, 0}.
// grid(67), 256 thr.
// ---------------------------------------------------------------------------
__global__ __launch_bounds__(256) void prep_w(const float* __restrict__ wq,
                                              const float* __restrict__ wp,
                                              const float* __restrict__ dc_b,
                                              const float* __restrict__ dc1_w,
                                              const float* __restrict__ dc1_b,
                                              const float* __restrict__ rpb,
                                              ushort_t* __restrict__ wq16,
                                              ushort_t* __restrict__ wp16,
                                              float* __restrict__ wattn) {
    int idx = blockIdx.x * 256 + threadIdx.x;   // 16384 float4 units + wattn slots
    if (idx >= 16384) {
        int t = idx - 16384;                    // need 576 = 8h * 72(ch*9+ka)
        if (t < 576) {
            int h = t / 72, r = t - h * 72;     // r = ch*9 + ka
            int ka = r % 9;
            float db = dc_b[r] + dc1_b[r];
            float* w = wattn + t * 12;          // t == (h*8+ch)*9 + ka
            #pragma unroll
            for (int j = 0; j < 9; ++j) w[j] = dc1_w[r * 9 + j];
            w[9]  = db + rpb[h * 9 + ka];       // K-branch bias (incl. rpb)
            w[10] = db;                         // V-branch bias
            w[11] = 0.f;
        }
        return;
    }
    const float* src; ushort_t* dst; int off;
    if (idx < 12288) { src = wq; dst = wq16; off = idx * 4; }
    else             { src = wp; dst = wp16; off = (idx - 12288) * 4; }
    float4 v = *(const float4*)(src + off);
    uint2 st = { pk(v.x, v.y), pk(v.z, v.w) };
    *(uint2*)(dst + off) = st;
}

// ---------------------------------------------------------------------------
// qkv v4: A operand REGISTER-DIRECT. Each lane loads its own MFMA A-fragment
// elements straight from x fp32 with transposed per-lane addressing
// (lane ml -> pos m0+ml, kg -> ch octet (ks*4+kg)*8; each load instr =
// 4 x 64B segments), packs to bf16 in-register (apk[8] = 32 VGPR). No LDS
// for A: removes the 64-load->pack->ds_write->barrier->ds_read chain.
// LDS = wb only 48KB -> 3 blk/CU (was 2). B staging/fragments unchanged.
// grid (49, 2, 16), 256 thr.
// ---------------------------------------------------------------------------
__global__ __launch_bounds__(256) void qkv_mfma(const float* __restrict__ x,
                                                const ushort_t* __restrict__ wq16,
                                                const float* __restrict__ bias,
                                                ushort_t* __restrict__ f16) {
    __shared__ __align__(16) ushort_t wb[96 * 256];
    const int tid = threadIdx.x;
    const int p0 = blockIdx.x * 64, o0 = blockIdx.y * 96, b = blockIdx.z;

    // B: async GLL (rows 512B, chunk q stored at q^(n&7))
    #pragma unroll
    for (int it = 0; it < 12; ++it) {
        int idx = it * 256 + tid;
        int n = idx >> 5, q = idx & 31, qs = q ^ (n & 7);
        gll16(wq16 + (size_t)(o0 + n) * 256 + qs * 8, &wb[idx * 8]);
    }

    const int lane = tid & 63;
    const int wid  = tid >> 6;
    const int m0   = wid * 16;
    const int ml   = lane & 15;
    const int kg   = lane >> 4;

    // A: direct per-lane loads, overlap the async B staging
    const float* xp = x + (size_t)b * 256 * POS + p0 + m0 + ml;
    uint4 apk[8];
    #pragma unroll
    for (int ks = 0; ks < 8; ++ks) {
        const float* xc = xp + (size_t)((ks * 4 + kg) * 8) * POS;
        apk[ks] = (uint4){ pk(xc[0],       xc[POS]),
                           pk(xc[2 * POS], xc[3 * POS]),
                           pk(xc[4 * POS], xc[5 * POS]),
                           pk(xc[6 * POS], xc[7 * POS]) };
    }
    __syncthreads();

    f32x4 acc[6];
    #pragma unroll
    for (int u = 0; u < 6; ++u) acc[u] = (f32x4){0.f, 0.f, 0.f, 0.f};

    #pragma unroll
    for (int ks = 0; ks < 8; ++ks) {
        const int pj = ((ks * 4 + kg) ^ (ml & 7)) * 8;   // B swizzled chunk
        union { uint4 u4; bf16x8 bf; } ac; ac.u4 = apk[ks];
        #pragma unroll
        for (int u = 0; u < 6; ++u) {
            bf16x8 bf = *(const bf16x8*)&wb[(u * 16 + ml) * 256 + pj];
            acc[u] = __builtin_amdgcn_mfma_f32_16x16x32_bf16(ac.bf, bf, acc[u], 0, 0, 0);
        }
    }

    #pragma unroll
    for (int u = 0; u < 6; ++u) {
        int o = o0 + u * 16 + ml;
        float bj = bias[o];
        uint2 st = { pk(acc[u][0] + bj, acc[u][1] + bj),
                     pk(acc[u][2] + bj, acc[u][3] + bj) };
        *(uint2*)(f16 + ((size_t)b * QKVC + o) * POS + p0 + m0 + kg * 4) = st;
    }
}

// ---------------------------------------------------------------------------
// attn: EXACT R6 body (proven 44.8us, VGPR 56): two-pass, bit-packed
// k|(v<<16) LDS, padded halo rows, coalesced u32 staging, per-ch fp32
// stores to aout [b][oc][pos] (coalesced; R7's [pos][64] scatter reverted).
// TBH=8, grid (7, 8, 16), 448 thr, LDS 19.2 KB.
// ---------------------------------------------------------------------------
#define TBH 8
#define HROW (TBH + 2)              // 10
#define HCOL 60                     // padded: [0]unused [1]L [2..57]int [58]R [59]unused
__global__ __launch_bounds__(448) void attn_kernel(const ushort_t* __restrict__ f16,
                                                   const float* __restrict__ wattn,
                                                   float* __restrict__ aout) {
    __shared__ __align__(16) unsigned int kvbuf[CH][HROW][HCOL];  // k | (v<<16)

    const int tid = threadIdx.x;
    const int ty0 = blockIdx.x * TBH;
    const int h   = blockIdx.y;
    const int b   = blockIdx.z;
    const ushort_t* fb = f16 + ((size_t)b * QKVC + h * 24) * POS;

    const int ly  = tid / WW;           // 0..7
    const int lx  = tid - ly * WW;
    const int pos = (ty0 + ly) * WW + lx;

    // q loads issued BEFORE staging: latency overlaps the stage loop
    float q[CH];
    #pragma unroll
    for (int ch = 0; ch < CH; ++ch) q[ch] = bu2f(fb[ch * POS + pos]) * SCALE;

    // zero L/R border columns (incl. corner rows)
    if (tid < 80) {
        int ch = tid / 10, row = tid - ch * 10;
        kvbuf[ch][row][1]  = 0;
        kvbuf[ch][row][58] = 0;
    }
    // interior: 8ch x 10row x 28 dword-pairs = 2240 tasks, 5 per thread
    #pragma unroll
    for (int it = 0; it < 5; ++it) {
        int idx  = it * 448 + tid;
        int ch   = idx / 280;
        int rem  = idx - ch * 280;
        int row  = rem / 28;
        int dcol = rem - row * 28;
        int gy   = ty0 + row - 1;
        unsigned int kk = 0, vv = 0;
        if (gy >= 0 && gy < HH) {           // wave-mostly-uniform row check
            int o = gy * WW + dcol * 2;
            kk = *(const unsigned int*)(fb + (8  + ch) * POS + o);
            vv = *(const unsigned int*)(fb + (16 + ch) * POS + o);
        }
        uint2 w;
        w.x = (kk & 0xffffu) | (vv << 16);
        w.y = (kk >> 16)     | (vv & 0xffff0000u);
        *(uint2*)&kvbuf[ch][row][2 + dcol * 2] = w;
    }
    __syncthreads();

    // per-(h,ch) fused weights: uniform -> s_load quads
    const float4* wh = (const float4*)wattn + (size_t)h * 8 * 27;

    // ---- pass 1: K-conv -> logits ----
    float logits[9];
    #pragma unroll
    for (int ka = 0; ka < 9; ++ka) logits[ka] = 0.f;
    #pragma unroll
    for (int ch = 0; ch < CH; ++ch) {
        float nk[9];
        #pragma unroll
        for (int dy = 0; dy < 3; ++dy)
            #pragma unroll
            for (int dx = 0; dx < 3; ++dx)
                nk[dy * 3 + dx] = lo2f(kvbuf[ch][ly + dy][lx + 1 + dx]);
        const float qc = q[ch];
        const float4* wp = wh + ch * 27;
        #pragma unroll
        for (int ka = 0; ka < 9; ++ka) {
            float4 a4 = wp[ka * 3 + 0];
            float4 b4 = wp[ka * 3 + 1];
            float4 c4 = wp[ka * 3 + 2];
            float kv = nk[ka] + c4.y;
            kv += nk[0]*a4.x + nk[1]*a4.y + nk[2]*a4.z + nk[3]*a4.w;
            kv += nk[4]*b4.x + nk[5]*b4.y + nk[6]*b4.z + nk[7]*b4.w;
            kv += nk[8]*c4.x;
            logits[ka] += qc * kv;
        }
    }

    // ---- softmax ----
    float m = logits[0];
    #pragma unroll
    for (int ka = 1; ka < 9; ++ka) m = fmaxf(m, logits[ka]);
    float att[9];
    float s = 0.f;
    #pragma unroll
    for (int ka = 0; ka < 9; ++ka) { att[ka] = __expf(logits[ka] - m); s += att[ka]; }
    float inv = 1.f / s;
    #pragma unroll
    for (int ka = 0; ka < 9; ++ka) att[ka] *= inv;

    // ---- pass 2: V-conv -> weighted sum, store per-ch (minimal live state) ----
    float* ap = aout + ((size_t)b * OC + h * CH) * POS + pos;
    #pragma unroll
    for (int ch = 0; ch < CH; ++ch) {
        float nv[9];
        #pragma unroll
        for (int dy = 0; dy < 3; ++dy)
            #pragma unroll
            for (int dx = 0; dx < 3; ++dx)
                nv[dy * 3 + dx] = hi2f(kvbuf[ch][ly + dy][lx + 1 + dx]);
        const float4* wp = wh + ch * 27;
        float o = 0.f;
        #pragma unroll
        for (int ka = 0; ka < 9; ++ka) {
            float4 a4 = wp[ka * 3 + 0];
            float4 b4 = wp[ka * 3 + 1];
            float4 c4 = wp[ka * 3 + 2];
            float vv = nv[ka] + c4.z;
            vv += nv[0]*a4.x + nv[1]*a4.y + nv[2]*a4.z + nv[3]*a4.w;
            vv += nv[4]*b4.x + nv[5]*b4.y + nv[6]*b4.z + nv[7]*b4.w;
            vv += nv[8]*c4.x;
            o += att[ka] * vv;
        }
        ap[ch * POS] = o;
    }
}
#undef TBH

// ---------------------------------------------------------------------------
// proj v3: A operand register-direct from fp32 a [b][oc][pos] (same trick
// as qkv v4): 16 scalar loads/lane, pack in-register, apk[2] = 8 VGPR.
// Entire fp32 ld buffer + wa + pack pass + 2 barriers eliminated.
// LDS = wb only 16KB. Mtile=64, Ntile=128. grid (49, 2, 16), 256 thr.
// ---------------------------------------------------------------------------
__global__ __launch_bounds__(256) void proj_mfma(const float* __restrict__ a,
                                                 const ushort_t* __restrict__ wp16,
                                                 const float* __restrict__ bias,
                                                 float* __restrict__ out) {
    __shared__ __align__(16) ushort_t wb[128 * 64];
    const int tid = threadIdx.x;
    const int p0 = blockIdx.x * 64, o0 = blockIdx.y * 128, b = blockIdx.z;

    // B: 128 rows x 8 chunks = 1024 tasks (pre-swizzled wp16, rows 128B)
    #pragma unroll
    for (int it = 0; it < 4; ++it) {
        int idx = it * 256 + tid;
        int n = idx >> 3, q = idx & 7, qs = q ^ (n & 7);
        gll16(wp16 + (size_t)(o0 + n) * 64 + qs * 8, &wb[idx * 8]);
    }

    const int lane = tid & 63;
    const int wid  = tid >> 6;
    const int m0   = wid * 16;
    const int ml   = lane & 15;
    const int kg   = lane >> 4;

    // A: direct per-lane loads (k = (s*4+kg)*8 + j, pos = p0+m0+ml)
    const float* ap2 = a + (size_t)b * OC * POS + p0 + m0 + ml;
    uint4 apk[2];
    #pragma unroll
    for (int s = 0; s < 2; ++s) {
        const float* ac = ap2 + (size_t)((s * 4 + kg) * 8) * POS;
        apk[s] = (uint4){ pk(ac[0],       ac[POS]),
                          pk(ac[2 * POS], ac[3 * POS]),
                          pk(ac[4 * POS], ac[5 * POS]),
                          pk(ac[6 * POS], ac[7 * POS]) };
    }
    __syncthreads();

    f32x4 acc[8];
    #pragma unroll
    for (int u = 0; u < 8; ++u) acc[u] = (f32x4){0.f, 0.f, 0.f, 0.f};

    #pragma unroll
    for (int s = 0; s < 2; ++s) {
        const int pj = ((s * 4 + kg) ^ (ml & 7)) * 8;    // B swizzled chunk
        union { uint4 u4; bf16x8 bf; } ac; ac.u4 = apk[s];
        #pragma unroll
        for (int u = 0; u < 8; ++u) {
            bf16x8 bf = *(const bf16x8*)&wb[(u * 16 + ml) * 64 + pj];
            acc[u] = __builtin_amdgcn_mfma_f32_16x16x32_bf16(ac.bf, bf, acc[u], 0, 0, 0);
        }
    }

    #pragma unroll
    for (int u = 0; u < 8; ++u) {
        int o = o0 + u * 16 + ml;
        float bj = bias[o];
        float4 st = { acc[u][0] + bj, acc[u][1] + bj, acc[u][2] + bj, acc[u][3] + bj };
        *(float4*)(out + ((size_t)b * 256 + o) * POS + p0 + m0 + kg * 4) = st;
    }
}

// ---------------------------------------------------------------------------
extern "C" void kernel_launch(void* const* d_in, const int* in_sizes, int n_in,
                              void* d_out, int out_size, void* d_ws, size_t ws_size,
                              hipStream_t stream) {
    const float* x      = (const float*)d_in[0];
    const float* qkv_w  = (const float*)d_in[1];
    const float* qkv_b  = (const float*)d_in[2];
    const float* dc_b   = (const float*)d_in[3];
    const float* dc1_w  = (const float*)d_in[4];
    const float* dc1_b  = (const float*)d_in[5];
    const float* rpb    = (const float*)d_in[6];
    const float* proj_w = (const float*)d_in[7];
    const float* proj_b = (const float*)d_in[8];
    float* out = (float*)d_out;

    // ws layout (32.27 MB base):
    //   f16   bf16 16*192*3136 = 19.27 MB
    //   a     fp32 16*64*3136  = 12.85 MB
    //   wq16  96 KB, wp16 32 KB
    //   wattn 27 KB -- d_out fallback if ws exact (proj rewrites all of out).
    ushort_t* f16  = (ushort_t*)d_ws;
    float*    a    = (float*)(f16 + (size_t)BATCH * QKVC * POS);
    ushort_t* wq16 = (ushort_t*)(a + (size_t)BATCH * OC * POS);
    ushort_t* wp16 = wq16 + 192 * 256;

    const size_t WS_BASE = 32243712;        // bytes used by the four bufs above
    float* wattn = (ws_size >= WS_BASE + 6912 * sizeof(float))
                 ? (float*)((char*)d_ws + WS_BASE)
                 : (float*)d_out;           // scratch; proj rewrites all of out

    prep_w   <<<dim3(67),           256, 0, stream>>>(qkv_w, proj_w, dc_b, dc1_w,
                                                      dc1_b, rpb, wq16, wp16, wattn);
    qkv_mfma <<<dim3(49, 2, BATCH), 256, 0, stream>>>(x, wq16, qkv_b, f16);
    attn_kernel<<<dim3(7, NH, BATCH), 448, 0, stream>>>(f16, wattn, a);
    proj_mfma<<<dim3(49, 2, BATCH), 256, 0, stream>>>(a, wp16, proj_b, out);
}

// Round 9
// 180.060 us; speedup vs baseline: 1.2037x; 1.0017x over previous
//
#include <hip/hip_runtime.h>
#include <hip/hip_bf16.h>

#define BATCH 16
#define NH    8
#define CH    8
#define HH    56
#define WW    56
#define POS   3136          // 56*56 = 49*64
#define QKVC  192
#define OC    64
#define SCALE 0.17677669529663687f   // 32^-0.5

typedef unsigned short ushort_t;
typedef __attribute__((ext_vector_type(8))) short bf16x8;   // 8 bf16 = 4 VGPRs
typedef __attribute__((ext_vector_type(4))) float f32x4;

__device__ __forceinline__ unsigned short f2b(float f) {
    __hip_bfloat16 h = __float2bfloat16(f);
    union { __hip_bfloat16 h; unsigned short u; } c; c.h = h; return c.u;
}
__device__ __forceinline__ unsigned int pk(float lo, float hi) {
    return (unsigned int)f2b(lo) | ((unsigned int)f2b(hi) << 16);
}
__device__ __forceinline__ float bu2f(ushort_t u) {
    union { unsigned int v; float f; } c; c.v = ((unsigned int)u) << 16; return c.f;
}
__device__ __forceinline__ float lo2f(unsigned int w) {       // low bf16 -> f32
    union { unsigned int v; float f; } c; c.v = w << 16; return c.f;
}
__device__ __forceinline__ float hi2f(unsigned int w) {       // high bf16 -> f32
    union { unsigned int v; float f; } c; c.v = w & 0xffff0000u; return c.f;
}
// async 16B global->LDS (lane-linear dest within wave)
__device__ __forceinline__ void gll16(const ushort_t* g, ushort_t* l) {
    __builtin_amdgcn_global_load_lds((const __attribute__((address_space(1))) void*)g,
                                     (__attribute__((address_space(3))) void*)l, 16, 0, 0);
}

// ---------------------------------------------------------------------------
// prep_w: qkv_w (192x256) + proj_w (256x64) fp32 -> bf16, PLUS fused attn
// weight tensor wattn[h][ch][ka][12] = {w0..w8, db+rpb, db, 0}.
// grid(67), 256 thr.
// ---------------------------------------------------------------------------
__global__ __launch_bounds__(256) void prep_w(const float* __restrict__ wq,
                                              const float* __restrict__ wp,
                                              const float* __restrict__ dc_b,
                                              const float* __restrict__ dc1_w,
                                              const float* __restrict__ dc1_b,
                                              const float* __restrict__ rpb,
                                              ushort_t* __restrict__ wq16,
                                              ushort_t* __restrict__ wp16,
                                              float* __restrict__ wattn) {
    int idx = blockIdx.x * 256 + threadIdx.x;   // 16384 float4 units + wattn slots
    if (idx >= 16384) {
        int t = idx - 16384;                    // need 576 = 8h * 72(ch*9+ka)
        if (t < 576) {
            int h = t / 72, r = t - h * 72;     // r = ch*9 + ka
            int ka = r % 9;
            float db = dc_b[r] + dc1_b[r];
            float* w = wattn + t * 12;          // t == (h*8+ch)*9 + ka
            #pragma unroll
            for (int j = 0; j < 9; ++j) w[j] = dc1_w[r * 9 + j];
            w[9]  = db + rpb[h * 9 + ka];       // K-branch bias (incl. rpb)
            w[10] = db;                         // V-branch bias
            w[11] = 0.f;
        }
        return;
    }
    const float* src; ushort_t* dst; int off;
    if (idx < 12288) { src = wq; dst = wq16; off = idx * 4; }
    else             { src = wp; dst = wp16; off = (idx - 12288) * 4; }
    float4 v = *(const float4*)(src + off);
    uint2 st = { pk(v.x, v.y), pk(v.z, v.w) };
    *(uint2*)(dst + off) = st;
}

// ---------------------------------------------------------------------------
// qkv v5: register-direct A (R8's win) + BOTH o-halves per block (R6's
// x-read-once). A = apk[8] in VGPRs, loaded ONCE, reused for both halves;
// mid-kernel restage is only wb's 12 gll16 + 2 barriers (R6's slow A-chain
// is gone). x traffic halves vs R8 (51.4 MB, was 103) -> f16 stays
// L2-resident for attn (R8's attn regression = f16 evicted by the doubled
// x stream). LDS 48KB = 3 blk/CU, grid (49, 1, 16) = 784 blocks, 256 thr.
// ---------------------------------------------------------------------------
__global__ __launch_bounds__(256) void qkv_mfma(const float* __restrict__ x,
                                                const ushort_t* __restrict__ wq16,
                                                const float* __restrict__ bias,
                                                ushort_t* __restrict__ f16) {
    __shared__ __align__(16) ushort_t wb[96 * 256];
    const int tid = threadIdx.x;
    const int p0 = blockIdx.x * 64, b = blockIdx.z;

    // B half 0: async GLL (rows 512B, chunk q stored at q^(n&7))
    #pragma unroll
    for (int it = 0; it < 12; ++it) {
        int idx = it * 256 + tid;
        int n = idx >> 5, q = idx & 31, qs = q ^ (n & 7);
        gll16(wq16 + (size_t)n * 256 + qs * 8, &wb[idx * 8]);
    }

    const int lane = tid & 63;
    const int wid  = tid >> 6;
    const int m0   = wid * 16;
    const int ml   = lane & 15;
    const int kg   = lane >> 4;

    // A: direct per-lane loads (once, reused across both halves),
    // overlapping the async B staging
    const float* xp = x + (size_t)b * 256 * POS + p0 + m0 + ml;
    uint4 apk[8];
    #pragma unroll
    for (int ks = 0; ks < 8; ++ks) {
        const float* xc = xp + (size_t)((ks * 4 + kg) * 8) * POS;
        apk[ks] = (uint4){ pk(xc[0],       xc[POS]),
                           pk(xc[2 * POS], xc[3 * POS]),
                           pk(xc[4 * POS], xc[5 * POS]),
                           pk(xc[6 * POS], xc[7 * POS]) };
    }
    __syncthreads();

    #pragma unroll
    for (int half = 0; half < 2; ++half) {
        f32x4 acc[6];
        #pragma unroll
        for (int u = 0; u < 6; ++u) acc[u] = (f32x4){0.f, 0.f, 0.f, 0.f};

        #pragma unroll
        for (int ks = 0; ks < 8; ++ks) {
            const int pj = ((ks * 4 + kg) ^ (ml & 7)) * 8;   // B swizzled chunk
            union { uint4 u4; bf16x8 bf; } ac; ac.u4 = apk[ks];
            #pragma unroll
            for (int u = 0; u < 6; ++u) {
                bf16x8 bf = *(const bf16x8*)&wb[(u * 16 + ml) * 256 + pj];
                acc[u] = __builtin_amdgcn_mfma_f32_16x16x32_bf16(ac.bf, bf, acc[u], 0, 0, 0);
            }
        }

        #pragma unroll
        for (int u = 0; u < 6; ++u) {
            int o = half * 96 + u * 16 + ml;
            float bj = bias[o];
            uint2 st = { pk(acc[u][0] + bj, acc[u][1] + bj),
                         pk(acc[u][2] + bj, acc[u][3] + bj) };
            *(uint2*)(f16 + ((size_t)b * QKVC + o) * POS + p0 + m0 + kg * 4) = st;
        }

        if (half == 0) {
            __syncthreads();            // all wb reads of half 0 complete
            #pragma unroll
            for (int it = 0; it < 12; ++it) {
                int idx = it * 256 + tid;
                int n = idx >> 5, q = idx & 31, qs = q ^ (n & 7);
                gll16(wq16 + (size_t)(96 + n) * 256 + qs * 8, &wb[idx * 8]);
            }
            __syncthreads();            // drains vmcnt before half-1 reads
        }
    }
}

// ---------------------------------------------------------------------------
// attn: EXACT R6/R8 body (proven 44.8us @ R6): two-pass, bit-packed
// k|(v<<16) LDS, padded halo rows, coalesced u32 staging, per-ch fp32
// stores to aout [b][oc][pos]. TBH=8, grid (7, 8, 16), 448 thr, LDS 19.2 KB.
// ---------------------------------------------------------------------------
#define TBH 8
#define HROW (TBH + 2)              // 10
#define HCOL 60                     // padded: [0]unused [1]L [2..57]int [58]R [59]unused
__global__ __launch_bounds__(448) void attn_kernel(const ushort_t* __restrict__ f16,
                                                   const float* __restrict__ wattn,
                                                   float* __restrict__ aout) {
    __shared__ __align__(16) unsigned int kvbuf[CH][HROW][HCOL];  // k | (v<<16)

    const int tid = threadIdx.x;
    const int ty0 = blockIdx.x * TBH;
    const int h   = blockIdx.y;
    const int b   = blockIdx.z;
    const ushort_t* fb = f16 + ((size_t)b * QKVC + h * 24) * POS;

    const int ly  = tid / WW;           // 0..7
    const int lx  = tid - ly * WW;
    const int pos = (ty0 + ly) * WW + lx;

    // q loads issued BEFORE staging: latency overlaps the stage loop
    float q[CH];
    #pragma unroll
    for (int ch = 0; ch < CH; ++ch) q[ch] = bu2f(fb[ch * POS + pos]) * SCALE;

    // zero L/R border columns (incl. corner rows)
    if (tid < 80) {
        int ch = tid / 10, row = tid - ch * 10;
        kvbuf[ch][row][1]  = 0;
        kvbuf[ch][row][58] = 0;
    }
    // interior: 8ch x 10row x 28 dword-pairs = 2240 tasks, 5 per thread
    #pragma unroll
    for (int it = 0; it < 5; ++it) {
        int idx  = it * 448 + tid;
        int ch   = idx / 280;
        int rem  = idx - ch * 280;
        int row  = rem / 28;
        int dcol = rem - row * 28;
        int gy   = ty0 + row - 1;
        unsigned int kk = 0, vv = 0;
        if (gy >= 0 && gy < HH) {           // wave-mostly-uniform row check
            int o = gy * WW + dcol * 2;
            kk = *(const unsigned int*)(fb + (8  + ch) * POS + o);
            vv = *(const unsigned int*)(fb + (16 + ch) * POS + o);
        }
        uint2 w;
        w.x = (kk & 0xffffu) | (vv << 16);
        w.y = (kk >> 16)     | (vv & 0xffff0000u);
        *(uint2*)&kvbuf[ch][row][2 + dcol * 2] = w;
    }
    __syncthreads();

    // per-(h,ch) fused weights: uniform -> s_load quads
    const float4* wh = (const float4*)wattn + (size_t)h * 8 * 27;

    // ---- pass 1: K-conv -> logits ----
    float logits[9];
    #pragma unroll
    for (int ka = 0; ka < 9; ++ka) logits[ka] = 0.f;
    #pragma unroll
    for (int ch = 0; ch < CH; ++ch) {
        float nk[9];
        #pragma unroll
        for (int dy = 0; dy < 3; ++dy)
            #pragma unroll
            for (int dx = 0; dx < 3; ++dx)
                nk[dy * 3 + dx] = lo2f(kvbuf[ch][ly + dy][lx + 1 + dx]);
        const float qc = q[ch];
        const float4* wp = wh + ch * 27;
        #pragma unroll
        for (int ka = 0; ka < 9; ++ka) {
            float4 a4 = wp[ka * 3 + 0];
            float4 b4 = wp[ka * 3 + 1];
            float4 c4 = wp[ka * 3 + 2];
            float kv = nk[ka] + c4.y;
            kv += nk[0]*a4.x + nk[1]*a4.y + nk[2]*a4.z + nk[3]*a4.w;
            kv += nk[4]*b4.x + nk[5]*b4.y + nk[6]*b4.z + nk[7]*b4.w;
            kv += nk[8]*c4.x;
            logits[ka] += qc * kv;
        }
    }

    // ---- softmax ----
    float m = logits[0];
    #pragma unroll
    for (int ka = 1; ka < 9; ++ka) m = fmaxf(m, logits[ka]);
    float att[9];
    float s = 0.f;
    #pragma unroll
    for (int ka = 0; ka < 9; ++ka) { att[ka] = __expf(logits[ka] - m); s += att[ka]; }
    float inv = 1.f / s;
    #pragma unroll
    for (int ka = 0; ka < 9; ++ka) att[ka] *= inv;

    // ---- pass 2: V-conv -> weighted sum, store per-ch (minimal live state) ----
    float* ap = aout + ((size_t)b * OC + h * CH) * POS + pos;
    #pragma unroll
    for (int ch = 0; ch < CH; ++ch) {
        float nv[9];
        #pragma unroll
        for (int dy = 0; dy < 3; ++dy)
            #pragma unroll
            for (int dx = 0; dx < 3; ++dx)
                nv[dy * 3 + dx] = hi2f(kvbuf[ch][ly + dy][lx + 1 + dx]);
        const float4* wp = wh + ch * 27;
        float o = 0.f;
        #pragma unroll
        for (int ka = 0; ka < 9; ++ka) {
            float4 a4 = wp[ka * 3 + 0];
            float4 b4 = wp[ka * 3 + 1];
            float4 c4 = wp[ka * 3 + 2];
            float vv = nv[ka] + c4.z;
            vv += nv[0]*a4.x + nv[1]*a4.y + nv[2]*a4.z + nv[3]*a4.w;
            vv += nv[4]*b4.x + nv[5]*b4.y + nv[6]*b4.z + nv[7]*b4.w;
            vv += nv[8]*c4.x;
            o += att[ka] * vv;
        }
        ap[ch * POS] = o;
    }
}
#undef TBH

// ---------------------------------------------------------------------------
// proj v3 (unchanged from R8): A register-direct from fp32 a [b][oc][pos].
// LDS = wb only 16KB. Mtile=64, Ntile=128. grid (49, 2, 16), 256 thr.
// ---------------------------------------------------------------------------
__global__ __launch_bounds__(256) void proj_mfma(const float* __restrict__ a,
                                                 const ushort_t* __restrict__ wp16,
                                                 const float* __restrict__ bias,
                                                 float* __restrict__ out) {
    __shared__ __align__(16) ushort_t wb[128 * 64];
    const int tid = threadIdx.x;
    const int p0 = blockIdx.x * 64, o0 = blockIdx.y * 128, b = blockIdx.z;

    // B: 128 rows x 8 chunks = 1024 tasks (pre-swizzled wp16, rows 128B)
    #pragma unroll
    for (int it = 0; it < 4; ++it) {
        int idx = it * 256 + tid;
        int n = idx >> 3, q = idx & 7, qs = q ^ (n & 7);
        gll16(wp16 + (size_t)(o0 + n) * 64 + qs * 8, &wb[idx * 8]);
    }

    const int lane = tid & 63;
    const int wid  = tid >> 6;
    const int m0   = wid * 16;
    const int ml   = lane & 15;
    const int kg   = lane >> 4;

    // A: direct per-lane loads (k = (s*4+kg)*8 + j, pos = p0+m0+ml)
    const float* ap2 = a + (size_t)b * OC * POS + p0 + m0 + ml;
    uint4 apk[2];
    #pragma unroll
    for (int s = 0; s < 2; ++s) {
        const float* ac = ap2 + (size_t)((s * 4 + kg) * 8) * POS;
        apk[s] = (uint4){ pk(ac[0],       ac[POS]),
                          pk(ac[2 * POS], ac[3 * POS]),
                          pk(ac[4 * POS], ac[5 * POS]),
                          pk(ac[6 * POS], ac[7 * POS]) };
    }
    __syncthreads();

    f32x4 acc[8];
    #pragma unroll
    for (int u = 0; u < 8; ++u) acc[u] = (f32x4){0.f, 0.f, 0.f, 0.f};

    #pragma unroll
    for (int s = 0; s < 2; ++s) {
        const int pj = ((s * 4 + kg) ^ (ml & 7)) * 8;    // B swizzled chunk
        union { uint4 u4; bf16x8 bf; } ac; ac.u4 = apk[s];
        #pragma unroll
        for (int u = 0; u < 8; ++u) {
            bf16x8 bf = *(const bf16x8*)&wb[(u * 16 + ml) * 64 + pj];
            acc[u] = __builtin_amdgcn_mfma_f32_16x16x32_bf16(ac.bf, bf, acc[u], 0, 0, 0);
        }
    }

    #pragma unroll
    for (int u = 0; u < 8; ++u) {
        int o = o0 + u * 16 + ml;
        float bj = bias[o];
        float4 st = { acc[u][0] + bj, acc[u][1] + bj, acc[u][2] + bj, acc[u][3] + bj };
        *(float4*)(out + ((size_t)b * 256 + o) * POS + p0 + m0 + kg * 4) = st;
    }
}

// ---------------------------------------------------------------------------
extern "C" void kernel_launch(void* const* d_in, const int* in_sizes, int n_in,
                              void* d_out, int out_size, void* d_ws, size_t ws_size,
                              hipStream_t stream) {
    const float* x      = (const float*)d_in[0];
    const float* qkv_w  = (const float*)d_in[1];
    const float* qkv_b  = (const float*)d_in[2];
    const float* dc_b   = (const float*)d_in[3];
    const float* dc1_w  = (const float*)d_in[4];
    const float* dc1_b  = (const float*)d_in[5];
    const float* rpb    = (const float*)d_in[6];
    const float* proj_w = (const float*)d_in[7];
    const float* proj_b = (const float*)d_in[8];
    float* out = (float*)d_out;

    // ws layout (32.27 MB base):
    //   f16   bf16 16*192*3136 = 19.27 MB
    //   a     fp32 16*64*3136  = 12.85 MB
    //   wq16  96 KB, wp16 32 KB
    //   wattn 27 KB -- d_out fallback if ws exact (proj rewrites all of out).
    ushort_t* f16  = (ushort_t*)d_ws;
    float*    a    = (float*)(f16 + (size_t)BATCH * QKVC * POS);
    ushort_t* wq16 = (ushort_t*)(a + (size_t)BATCH * OC * POS);
    ushort_t* wp16 = wq16 + 192 * 256;

    const size_t WS_BASE = 32243712;        // bytes used by the four bufs above
    float* wattn = (ws_size >= WS_BASE + 6912 * sizeof(float))
                 ? (float*)((char*)d_ws + WS_BASE)
                 : (float*)d_out;           // scratch; proj rewrites all of out

    prep_w   <<<dim3(67),           256, 0, stream>>>(qkv_w, proj_w, dc_b, dc1_w,
                                                      dc1_b, rpb, wq16, wp16, wattn);
    qkv_mfma <<<dim3(49, 1, BATCH), 256, 0, stream>>>(x, wq16, qkv_b, f16);
    attn_kernel<<<dim3(7, NH, BATCH), 448, 0, stream>>>(f16, wattn, a);
    proj_mfma<<<dim3(49, 2, BATCH), 256, 0, stream>>>(a, wp16, proj_b, out);
}